// Round 14
// baseline (241.248 us; speedup 1.0000x reference)
//
#include <hip/hip_runtime.h>
#include <hip/hip_bf16.h>

#define EMB 128
#define HID 11
#define PAIRS 2   // pair-units per stage; stage = 4 CONSECUTIVE tokens

typedef float f32x4 __attribute__((ext_vector_type(4)));
typedef int   i32x4 __attribute__((ext_vector_type(4)));

// tanh(x) = sign(x) * (1 - 2/(exp(2|x|)+1)); v_exp_f32 + v_rcp_f32 fast path.
__device__ __forceinline__ float fast_tanh(float x) {
    float ax = fabsf(x);
    float e  = __expf(2.0f * ax);
    float r  = 1.0f - 2.0f * __builtin_amdgcn_rcpf(e + 1.0f);
    return copysignf(r, x);
}

// R14 theory: L2 as a PURE WRITE BUFFER. R13 showed plain stores lose when
// reads allocate into L2 (158us); fill kernel shows plain write-back does
// 6.9TB/s when L2 only holds the write stream. So: ALL loads nontemporal
// (no L2 allocate; emb stays hot in the 256MB L3), stores PLAIN write-back
// (aggregate in L2, burst-drain like the fill kernel).
// Also: the 4 group tokens are consecutive -> value/var_id/cmask fetched as
// THREE uniform x4 NT loads (was 6 broadcast dwords), pm computed directly
// from id4 (no shfls).
// Locked-in: dense write front (R6), depth-1 pipeline (R5), no tight VGPR
// cap (R3), stage = 4 consecutive tokens / 2KB bursts (R12).
__global__ __launch_bounds__(256, 2) void tabenc_kernel(
    const float* __restrict__ value,
    const int*   __restrict__ var_id,
    const int*   __restrict__ cmask,
    const float* __restrict__ W1,
    const float* __restrict__ b1,
    const float* __restrict__ W2,
    const float* __restrict__ emb,
    float*       __restrict__ out_sum,
    float*       __restrict__ out_pm,
    int n_tokens)
{
    const int tid  = threadIdx.x;
    const int lane = tid & 63;
    const int half = lane >> 5;
    const int sub  = lane & 31;
    const int sb   = lane & 32;      // shfl source base for this half-wave
    const int c0   = sub << 2;

    f32x4 w2[HID];
#pragma unroll
    for (int h = 0; h < HID; ++h)
        w2[h] = *reinterpret_cast<const f32x4*>(W2 + h * EMB + c0);

    float w1v = 0.0f, b1v = 0.0f;
    if (sub < HID) { w1v = W1[sub]; b1v = b1[sub]; }

    const int gwave  = (blockIdx.x << 2) + (tid >> 6);
    const int nwaves = gridDim.x << 2;
    const int ngrp   = (n_tokens + 3) >> 2;   // groups of 4 consecutive tokens
    const int tmax   = n_tokens - 1;

    if (gwave >= ngrp) return;

    f32x4 vC4;  i32x4 idC4, cmC4;  f32x4 eC[PAIRS];
    f32x4 vN4;  i32x4 idN4, cmN4;  f32x4 eN[PAIRS];

    auto LOAD = [&](int g, f32x4& v4, i32x4& id4, i32x4& cm4, f32x4* e) {
        if (g > ngrp - 1) g = ngrp - 1;
        const int t0 = g << 2;
        if (t0 + 3 <= tmax) {         // wave-uniform branch
            v4  = __builtin_nontemporal_load(
                      reinterpret_cast<const f32x4*>(value  + t0));
            id4 = __builtin_nontemporal_load(
                      reinterpret_cast<const i32x4*>(var_id + t0));
            cm4 = __builtin_nontemporal_load(
                      reinterpret_cast<const i32x4*>(cmask  + t0));
        } else {                       // tail group (never for 819200)
#pragma unroll
            for (int j = 0; j < 4; ++j) {
                int t = t0 + j; if (t > tmax) t = tmax;
                v4[j] = value[t]; id4[j] = var_id[t]; cm4[j] = cmask[t];
            }
        }
#pragma unroll
        for (int k = 0; k < PAIRS; ++k) {
            const int j0 = k << 1;
            const int idk = half ? id4[j0 + 1] : id4[j0];  // const-idx select
            e[k] = __builtin_nontemporal_load(
                       reinterpret_cast<const f32x4*>(emb + (long)idk * EMB + c0));
        }
    };

    LOAD(gwave, vC4, idC4, cmC4, eC);

    for (int g = gwave; g < ngrp; g += nwaves) {
        // ---- prefetch next stage (clamped, unconditional) ----
        LOAD(g + nwaves, vN4, idN4, cmN4, eN);

        // ---- compute current stage ----
        float hv[PAIRS], fm[PAIRS];
#pragma unroll
        for (int k = 0; k < PAIRS; ++k) {
            const int j0 = k << 1;
            const float vk = half ? vC4[j0 + 1] : vC4[j0];
            fm[k] = (float)(half ? cmC4[j0 + 1] : cmC4[j0]);
            hv[k] = fast_tanh(fmaf(vk, w1v, b1v));
        }

        f32x4 acc[PAIRS];
#pragma unroll
        for (int k = 0; k < PAIRS; ++k)
            acc[k] = (f32x4){0.f, 0.f, 0.f, 0.f};

#pragma unroll
        for (int hh = 0; hh < HID; ++hh) {
#pragma unroll
            for (int k = 0; k < PAIRS; ++k) {
                const float kk = __shfl(hv[k], sb + hh, 64);
                acc[k] += kk * w2[hh];
            }
        }

        const int t0 = g << 2;
        const bool full = (t0 + 3 <= tmax);

        // ---- out_sum: one contiguous 2KB PLAIN write-back burst ----
#pragma unroll
        for (int k = 0; k < PAIRS; ++k) {
            const int tok = t0 + (k << 1) + half;
            if (full || tok <= tmax)
                *reinterpret_cast<f32x4*>(out_sum + (long)tok * EMB + c0) =
                    acc[k] * fm[k] + eC[k];
        }

        // ---- out_pm: one plain float4 store from id4 (no shfls) ----
        if (lane == 0) {
            if (full) {
                const f32x4 pm = (f32x4){(idC4[0] > 0) ? 1.0f : 0.0f,
                                         (idC4[1] > 0) ? 1.0f : 0.0f,
                                         (idC4[2] > 0) ? 1.0f : 0.0f,
                                         (idC4[3] > 0) ? 1.0f : 0.0f};
                *reinterpret_cast<f32x4*>(out_pm + t0) = pm;
            } else {                   // tail group (never for 819200)
                for (int t = t0; t <= tmax; ++t)
                    out_pm[t] = (idC4[t - t0] > 0) ? 1.0f : 0.0f;
            }
        }

        // ---- rotate pipeline regs ----
        vC4 = vN4; idC4 = idN4; cmC4 = cmN4;
#pragma unroll
        for (int k = 0; k < PAIRS; ++k) eC[k] = eN[k];
    }
}

extern "C" void kernel_launch(void* const* d_in, const int* in_sizes, int n_in,
                              void* d_out, int out_size, void* d_ws, size_t ws_size,
                              hipStream_t stream) {
    const float* value  = (const float*)d_in[0];
    const int*   var_id = (const int*)  d_in[1];
    const int*   cmask  = (const int*)  d_in[2];
    const float* W1     = (const float*)d_in[3];
    const float* b1     = (const float*)d_in[4];
    const float* W2     = (const float*)d_in[5];
    const float* emb    = (const float*)d_in[6];

    const int n_tokens = in_sizes[0];              // 4096*200 = 819200
    float* out_sum = (float*)d_out;                // [n_tokens, 128]
    float* out_pm  = (float*)d_out + (long long)n_tokens * EMB;  // [n_tokens]

    const int groups_needed = (n_tokens + 3) / 4;
    const int blocks_needed = (groups_needed + 3) / 4;
    const int grid = blocks_needed < 2048 ? blocks_needed : 2048;

    tabenc_kernel<<<grid, 256, 0, stream>>>(value, var_id, cmask, W1, b1, W2,
                                            emb, out_sum, out_pm, n_tokens);
}

// Round 15
// 101.909 us; speedup vs baseline: 2.3673x; 2.3673x over previous
//
#include <hip/hip_runtime.h>
#include <hip/hip_bf16.h>

#define EMB 128
#define HID 11
#define PAIRS 2   // pair-units per stage; stage = 4 CONSECUTIVE tokens

typedef float f32x4 __attribute__((ext_vector_type(4)));

// tanh(x) = sign(x) * (1 - 2/(exp(2|x|)+1)); v_exp_f32 + v_rcp_f32 fast path.
__device__ __forceinline__ float fast_tanh(float x) {
    float ax = fabsf(x);
    float e  = __expf(2.0f * ax);
    float r  = 1.0f - 2.0f * __builtin_amdgcn_rcpf(e + 1.0f);
    return copysignf(r, x);
}

// Store-policy ledger (locked): NT stores + regular loads (R7/R13/R14:
// plain stores 158-241us; NT 95.5). Dense write front (R6). No tight VGPR
// cap (R3). Stage = 4 consecutive tokens, clean f32x4 pm store (R12).
//
// R15 change: TWO-BANK output staging. ISA: a store holds its data VGPRs
// until vmcnt write-confirmation (~600-900cyc for NT). Single-bank loops
// stall every stage overwriting last stage's store regs. Here: compute
// stage A -> oA, compute stage B -> oB (oA live through B's compute ->
// distinct physregs), then batch-store A+B (4KB burst). Overwrite of each
// bank is a full stage after its store -> retire latency hidden.
__global__ __launch_bounds__(256, 2) void tabenc_kernel(
    const float* __restrict__ value,
    const int*   __restrict__ var_id,
    const int*   __restrict__ cmask,
    const float* __restrict__ W1,
    const float* __restrict__ b1,
    const float* __restrict__ W2,
    const float* __restrict__ emb,
    float*       __restrict__ out_sum,
    float*       __restrict__ out_pm,
    int n_tokens)
{
    const int tid  = threadIdx.x;
    const int lane = tid & 63;
    const int half = lane >> 5;
    const int sub  = lane & 31;
    const int sb   = lane & 32;      // shfl source base for this half-wave
    const int c0   = sub << 2;

    f32x4 w2[HID];
#pragma unroll
    for (int h = 0; h < HID; ++h)
        w2[h] = *reinterpret_cast<const f32x4*>(W2 + h * EMB + c0);

    float w1v = 0.0f, b1v = 0.0f;
    if (sub < HID) { w1v = W1[sub]; b1v = b1[sub]; }

    const int gwave  = (blockIdx.x << 2) + (tid >> 6);
    const int nwaves = gridDim.x << 2;
    const int ngrp   = (n_tokens + 3) >> 2;   // groups of 4 consecutive tokens
    const int tmax   = n_tokens - 1;

    if (gwave >= ngrp) return;

    float vC[PAIRS]; int idC[PAIRS]; float fmC[PAIRS]; f32x4 eC[PAIRS];
    float vN[PAIRS]; int idN[PAIRS]; float fmN[PAIRS]; f32x4 eN[PAIRS];

    auto LOAD = [&](int g, float* v, int* id, float* fm, f32x4* e) {
#pragma unroll
        for (int k = 0; k < PAIRS; ++k) {
            int t = (g << 2) + (k << 1) + half;
            if (t > tmax) t = tmax;     // clamp: branch-free, dup loads only
            v[k]  = value[t];
            id[k] = var_id[t];
            fm[k] = (float)cmask[t];
        }
#pragma unroll
        for (int k = 0; k < PAIRS; ++k)
            e[k] = *reinterpret_cast<const f32x4*>(emb + (long)id[k] * EMB + c0);
    };

    auto COMPUTE = [&](f32x4* o, f32x4& pm) {
        float hv[PAIRS];
#pragma unroll
        for (int k = 0; k < PAIRS; ++k)
            hv[k] = fast_tanh(fmaf(vC[k], w1v, b1v));

        f32x4 acc[PAIRS];
#pragma unroll
        for (int k = 0; k < PAIRS; ++k)
            acc[k] = (f32x4){0.f, 0.f, 0.f, 0.f};

#pragma unroll
        for (int hh = 0; hh < HID; ++hh) {
#pragma unroll
            for (int k = 0; k < PAIRS; ++k) {
                const float kk = __shfl(hv[k], sb + hh, 64);
                acc[k] += kk * w2[hh];
            }
        }
#pragma unroll
        for (int k = 0; k < PAIRS; ++k)
            o[k] = acc[k] * fmC[k] + eC[k];

        const float pA  = (idC[0] > 0) ? 1.0f : 0.0f;   // t0 + half
        const float pB  = (idC[1] > 0) ? 1.0f : 0.0f;   // t0 + 2 + half
        const float pA1 = __shfl(pA, 32, 64);           // t0 + 1
        const float pB1 = __shfl(pB, 32, 64);           // t0 + 3
        pm = (f32x4){pA, pA1, pB, pB1};                 // valid on lane 0
    };

    auto ROTATE = [&]() {
#pragma unroll
        for (int k = 0; k < PAIRS; ++k) {
            vC[k] = vN[k]; idC[k] = idN[k]; fmC[k] = fmN[k]; eC[k] = eN[k];
        }
    };

    auto STORE = [&](int g, const f32x4* o, const f32x4& pm) {
        const int t0 = g << 2;
        const bool full = (t0 + 3 <= tmax);
#pragma unroll
        for (int k = 0; k < PAIRS; ++k) {
            const int tok = t0 + (k << 1) + half;
            if (full || tok <= tmax)
                __builtin_nontemporal_store(o[k],
                    reinterpret_cast<f32x4*>(out_sum + (long)tok * EMB + c0));
        }
        if (lane == 0) {
            if (full) {
                __builtin_nontemporal_store(pm,
                    reinterpret_cast<f32x4*>(out_pm + t0));
            } else {                   // tail group (never for 819200)
                for (int t = t0; t <= tmax; ++t) out_pm[t] = pm[t - t0];
            }
        }
    };

    LOAD(gwave, vC, idC, fmC, eC);

    for (int g = gwave; g < ngrp; g += 2 * nwaves) {
        const int gB  = g + nwaves;
        const bool doB = (gB < ngrp);

        // ---- stage A: prefetch B inputs, compute A (no store yet) ----
        LOAD(gB, vN, idN, fmN, eN);
        f32x4 oA[PAIRS], pmA;
        COMPUTE(oA, pmA);
        ROTATE();

        // ---- stage B: prefetch next-A inputs, compute B ----
        f32x4 oB[PAIRS], pmB;
        if (doB) {
            LOAD(gB + nwaves, vN, idN, fmN, eN);
            COMPUTE(oB, pmB);
            ROTATE();
        }

        // ---- batched store phase: 4KB burst (A then B) ----
        STORE(g, oA, pmA);
        if (doB) STORE(gB, oB, pmB);
    }
}

extern "C" void kernel_launch(void* const* d_in, const int* in_sizes, int n_in,
                              void* d_out, int out_size, void* d_ws, size_t ws_size,
                              hipStream_t stream) {
    const float* value  = (const float*)d_in[0];
    const int*   var_id = (const int*)  d_in[1];
    const int*   cmask  = (const int*)  d_in[2];
    const float* W1     = (const float*)d_in[3];
    const float* b1     = (const float*)d_in[4];
    const float* W2     = (const float*)d_in[5];
    const float* emb    = (const float*)d_in[6];

    const int n_tokens = in_sizes[0];              // 4096*200 = 819200
    float* out_sum = (float*)d_out;                // [n_tokens, 128]
    float* out_pm  = (float*)d_out + (long long)n_tokens * EMB;  // [n_tokens]

    const int groups_needed = (n_tokens + 3) / 4;
    const int blocks_needed = (groups_needed + 3) / 4;
    const int grid = blocks_needed < 2048 ? blocks_needed : 2048;

    tabenc_kernel<<<grid, 256, 0, stream>>>(value, var_id, cmask, W1, b1, W2,
                                            emb, out_sum, out_pm, n_tokens);
}